// Round 21
// baseline (656.391 us; speedup 1.0000x reference)
//
#include <hip/hip_runtime.h>
#include <hip/hip_bf16.h>
#include <math.h>

typedef unsigned short u16;
typedef unsigned int   u32;
typedef __attribute__((ext_vector_type(8))) short bf16x8;
typedef __attribute__((ext_vector_type(4))) float f32x4;

#define LN_EPS 1e-5f
#define RS_QK  0.17677669529663687f   // 1/sqrt(32)

#define BFLO(u) __uint_as_float((u)<<16)
#define BFHI(u) __uint_as_float((u)&0xffff0000u)
#define UNPK(Wv_,p) const float p##0=BFLO((Wv_).x), p##1=BFHI((Wv_).x), \
                                p##2=BFLO((Wv_).y), p##3=BFHI((Wv_).y), \
                                p##4=BFLO((Wv_).z), p##5=BFHI((Wv_).z), \
                                p##6=BFLO((Wv_).w), p##7=BFHI((Wv_).w)
#define DOT8N(acc,va_,vb_,p) acc += (va_).x*p##0 + (va_).y*p##1 + (va_).z*p##2 + (va_).w*p##3 \
                                  + (vb_).x*p##4 + (vb_).y*p##5 + (vb_).z*p##6 + (vb_).w*p##7

__device__ __forceinline__ u16 f2bf(float x){   // software RNE (prep)
  u32 u = __float_as_uint(x);
  u32 r = (u + 0x7fffu + ((u>>16)&1u)) >> 16;
  return (u16)r;
}
__device__ __forceinline__ u16 f2bf_fast(float x){
  __hip_bfloat16 h = __float2bfloat16(x);
  return *(u16*)&h;
}

// weo B-frag via 4 volatile u32 loads (r11/r13/r16/r17-verified; never LICM-hoisted).
__device__ __forceinline__ bf16x8 lfrag(const u16* p){
  const volatile u32* q = (const volatile u32*)p;
  const u32 a=q[0], b=q[1], c=q[2], d=q[3];
  bf16x8 r;
  r[0]=(short)(a&0xffffu); r[1]=(short)(a>>16);
  r[2]=(short)(b&0xffffu); r[3]=(short)(b>>16);
  r[4]=(short)(c&0xffffu); r[5]=(short)(c>>16);
  r[6]=(short)(d&0xffffu); r[7]=(short)(d>>16);
  return r;
}

// ---------- prep: Wem/Wea/Weo in MFMA B-frag order; WE1/WE2 chunk-major (scalar FFN) ----------
__global__ void prep_weights(const float* __restrict__ Wem, const float* __restrict__ Wea,
                             const float* __restrict__ Weo, const float* __restrict__ WE1,
                             const float* __restrict__ WE2,
                             u16* __restrict__ wem_pk, u16* __restrict__ wea_pk,
                             u16* __restrict__ weo_pk, u16* __restrict__ we1_cm,
                             u16* __restrict__ we2_cm)
{
  int g = blockIdx.x*256 + threadIdx.x;
  if (g < 16384) {                    // Wem (64x256): nt<16, kb<2
    int i=g&7, lane=(g>>3)&63, kb=(g>>9)&1, nt=g>>10;
    wem_pk[g] = f2bf(Wem[(kb*32+(lane>>4)*8+i)*256 + nt*16 + (lane&15)]);
  } else if (g < 32768) {             // Wea
    int x=g-16384; int i=x&7, lane=(x>>3)&63, kb=(x>>9)&1, nt=x>>10;
    wea_pk[x] = f2bf(Wea[(kb*32+(lane>>4)*8+i)*256 + nt*16 + (lane&15)]);
  } else if (g < 49152) {             // Weo (256x64): nt<4, kb<8
    int x=g-32768; int i=x&7, lane=(x>>3)&63, kb=(x>>9)&7, nt=x>>12;
    weo_pk[x] = f2bf(Weo[(kb*32+(lane>>4)*8+i)*64 + nt*16 + (lane&15)]);
  } else if (g < 57344) {             // WE1 (64x128): [cc<8][h<128][k<8]
    int x=g-49152; int cc=x>>10, h=(x>>3)&127, k=x&7;
    we1_cm[x] = f2bf(WE1[(cc*8+k)*128 + h]);
  } else {                            // WE2 (128x64): [cc<16][e<64][k<8]
    int x=g-57344; int cc=x>>9, e=(x>>3)&63, k=x&7;
    we2_cm[x] = f2bf(WE2[(cc*8+k)*64 + e]);
  }
}

// ---------- QKV: Q/K/V = (X@W + b) * mask, 4 rows per block; unroll-4 weight stream ----------
__launch_bounds__(256)
__global__ void qkv_kernel(const float* __restrict__ X, const int* __restrict__ mask,
  const float* __restrict__ Wq, const float* __restrict__ bq,
  const float* __restrict__ Wk, const float* __restrict__ bk,
  const float* __restrict__ Wv, const float* __restrict__ bv,
  float* __restrict__ Q, float* __restrict__ K, float* __restrict__ V)
{
  const int t = threadIdx.x, d = t;
  const int r0 = blockIdx.x * 4;
  __shared__ float s_x[4][256];
  __shared__ float s_m[4];
#pragma unroll
  for (int rr=0;rr<4;++rr) s_x[rr][d] = X[(size_t)(r0+rr)*256 + d];
  if (t<4) s_m[t] = (mask[r0+t]!=0)?1.f:0.f;
  __syncthreads();
  float qa0=0,qa1=0,qa2=0,qa3=0;
  float ka0=0,ka1=0,ka2=0,ka3=0;
  float va0=0,va1=0,va2=0,va3=0;
#pragma unroll 4
  for (int c=0;c<256;++c){
    const float wq = Wq[c*256+d], wk = Wk[c*256+d], wv = Wv[c*256+d];
#define QKV1(rr) { const float xv = s_x[rr][c]; qa##rr+=xv*wq; ka##rr+=xv*wk; va##rr+=xv*wv; }
    QKV1(0) QKV1(1) QKV1(2) QKV1(3)
#undef QKV1
  }
  const float bqd=bq[d], bkd=bk[d], bvd=bv[d];
#define QKVW(rr) { const float mf = s_m[rr]; const size_t o = (size_t)(r0+rr)*256 + d; \
    Q[o]=(qa##rr+bqd)*mf; K[o]=(ka##rr+bkd)*mf; V[o]=(va##rr+bvd)*mf; }
  QKVW(0) QKVW(1) QKVW(2) QKVW(3)
#undef QKVW
}

// ---------- heavy: MFMA phases 1-3 (+lfrag weo), scalar phase 4 MERGED; E-tile prefetch (T14) ----------
__launch_bounds__(256, 2)
__global__ void heavy_kernel(const float* __restrict__ E, const int* __restrict__ mask,
  const float* __restrict__ Qg, const float* __restrict__ Kg, const float* __restrict__ Vg,
  const float* __restrict__ bem, const float* __restrict__ bea, const float* __restrict__ beo,
  const float* __restrict__ bE1, const float* __restrict__ bE2,
  const float* __restrict__ gE1, const float* __restrict__ bnE1,
  const float* __restrict__ gE2, const float* __restrict__ bnE2,
  const u16* __restrict__ wem_pk, const u16* __restrict__ wea_pk, const u16* __restrict__ weo_pk,
  const u16* __restrict__ we1_cm, const u16* __restrict__ we2_cm,
  float* __restrict__ WV, float* __restrict__ Eout)
{
  const int t  = threadIdx.x;
  const int w  = t>>6, l = t&63;
  const int lr = l&15, lh = l>>4;
  const int bi = blockIdx.x;
  const int rb = (bi >> 8) << 8;

  __shared__ u16   s_we1[8192];          // 16KB FFN W1 chunk-major (scalar path)
  __shared__ u16   s_we2[8192];          // 16KB FFN W2 chunk-major
  __shared__ float s_et[16][64];         // 4KB  f32 E tile
  __shared__ __align__(16) u16 s_eb[1024]; // 2KB bf16 E tile (swz)
  __shared__ __align__(16) u16 s_y[4096];  // 8KB bf16 Y (swz); phase-4 overlay: hid [16][128] f32
  __shared__ float s_ne[16][64];         // 4KB newE; phase-4 overlay: e1n (in-place)
  __shared__ float s_mask[256];          // 1KB

  {
    const uint4* s1 = (const uint4*)we1_cm; uint4* d1 = (uint4*)s_we1;
    const uint4* s2 = (const uint4*)we2_cm; uint4* d2 = (uint4*)s_we2;
    for (int k=t; k<1024; k+=256){ d1[k]=s1[k]; d2[k]=s2[k]; }
    s_mask[t] = (mask[rb + t] != 0) ? 1.f : 0.f;
  }
  const float mi = (mask[bi] != 0) ? 1.f : 0.f;

  // hoisted chunk-invariant Wem/Wea B fragments (64 VGPRs)
  bf16x8 bm0,bm1,bm2,bm3,bm4,bm5,bm6,bm7;
  bf16x8 ba0,ba1,ba2,ba3,ba4,ba5,ba6,ba7;
  {
    const bf16x8* pm = (const bf16x8*)wem_pk;
    const bf16x8* pa = (const bf16x8*)wea_pk;
#define LB(nt,kb,vm,va_) vm = pm[((4*w+nt)*2+kb)*64 + l]; va_ = pa[((4*w+nt)*2+kb)*64 + l];
    LB(0,0,bm0,ba0) LB(0,1,bm1,ba1) LB(1,0,bm2,ba2) LB(1,1,bm3,ba3)
    LB(2,0,bm4,ba4) LB(2,1,bm5,ba5) LB(3,0,bm6,ba6) LB(3,1,bm7,ba7)
#undef LB
  }

  const int dcol0=(4*w+0)*16+lr, dcol1=(4*w+1)*16+lr, dcol2=(4*w+2)*16+lr, dcol3=(4*w+3)*16+lr;
  const float qv0=Qg[(size_t)bi*256+dcol0], qv1=Qg[(size_t)bi*256+dcol1],
              qv2=Qg[(size_t)bi*256+dcol2], qv3=Qg[(size_t)bi*256+dcol3];
  const float bm_0=bem[dcol0], bm_1=bem[dcol1], bm_2=bem[dcol2], bm_3=bem[dcol3];
  const float ba_0=bea[dcol0], ba_1=bea[dcol1], ba_2=bea[dcol2], ba_3=bea[dcol3];

  float sm0=-3.0e38f, sm1=-3.0e38f, sm2=-3.0e38f, sm3=-3.0e38f;
  float sl0=0.f, sl1=0.f, sl2=0.f, sl3=0.f;
  float sa0=0.f, sa1=0.f, sa2=0.f, sa3=0.f;

  const int g4 = t>>5, r4 = t&31;      // phase-4 layout (row groups, 32-lane cols)

  // E-tile prefetch (T14 issue-early/write-late): ev holds chunk ch's tile slice
  float4 ev = ((const float4*)(E + (size_t)bi*256*64))[t];

  __syncthreads();

#pragma unroll 1
  for (int ch=0; ch<16; ++ch) {
    const int j0 = ch*16;
    {
      const int row = t>>4, c4 = (t&15)*4;
      *(float4*)&s_et[row][c4] = ev;
      ushort4 h; h.x=f2bf_fast(ev.x); h.y=f2bf_fast(ev.y); h.z=f2bf_fast(ev.z); h.w=f2bf_fast(ev.w);
      const int byt = (row*128 + c4*2) ^ ((row&7)<<4);
      *(ushort4*)((char*)s_eb + byt) = h;
    }
    if (ch < 15)   // issue next chunk's load; consumed only at next stage-write (5 barriers away)
      ev = ((const float4*)(E + ((size_t)bi*256 + j0 + 16)*64))[t];
    __syncthreads();

    // ---- phases 1+2 fused per nt (verified) ----
    const bf16x8 af0 = *(const bf16x8*)((char*)s_eb + ((lr*128 +  0 + lh*16) ^ ((lr&7)<<4)));
    const bf16x8 af1 = *(const bf16x8*)((char*)s_eb + ((lr*128 + 64 + lh*16) ^ ((lr&7)<<4)));
#define NTBLK(HM0,HM1,HA0,HA1, qvv,bmv,bav,dcv, smv,slv,sav) { \
    f32x4 e1f={0,0,0,0}, e2f={0,0,0,0}; \
    e1f = __builtin_amdgcn_mfma_f32_16x16x32_bf16(af0, HM0, e1f,0,0,0); \
    e1f = __builtin_amdgcn_mfma_f32_16x16x32_bf16(af1, HM1, e1f,0,0,0); \
    e2f = __builtin_amdgcn_mfma_f32_16x16x32_bf16(af0, HA0, e2f,0,0,0); \
    e2f = __builtin_amdgcn_mfma_f32_16x16x32_bf16(af1, HA1, e2f,0,0,0); \
    _Pragma("unroll") \
    for (int r=0;r<4;++r){ \
      const int jrow = lh*4+r; const int jr = j0+jrow; \
      const float mj = s_mask[jr]; const float pm = mi*mj; \
      const float e1 = (e1f[r]+bmv)*pm, e2 = (e2f[r]+bav)*pm; \
      float y = qvv * Kg[(size_t)(rb+jr)*256 + dcv] * RS_QK; \
      y = y*(e1+1.f)+e2; \
      *(u16*)((char*)s_y + ((jrow*512 + dcv*2) ^ ((jrow&7)<<4))) = f2bf_fast(y); \
      if (mj>0.f){ const float mn=fmaxf(smv,y); const float sc=__expf(smv-mn); \
        const float p=__expf(y-mn); \
        slv = slv*sc+p; sav = sav*sc + p*Vg[(size_t)(rb+jr)*256 + dcv]; smv=mn; } } }
    NTBLK(bm0,bm1,ba0,ba1, qv0,bm_0,ba_0,dcol0, sm0,sl0,sa0)
    NTBLK(bm2,bm3,ba2,ba3, qv1,bm_1,ba_1,dcol1, sm1,sl1,sa1)
    NTBLK(bm4,bm5,ba4,ba5, qv2,bm_2,ba_2,dcol2, sm2,sl2,sa2)
    NTBLK(bm6,bm7,ba6,ba7, qv3,bm_3,ba_3,dcol3, sm3,sl3,sa3)
#undef NTBLK
    __syncthreads();

    // ---- phase 3 (MFMA): newE = Y @ Weo; e-tile = w; B-frags via lfrag (verified) ----
    {
      f32x4 acc3 = {0,0,0,0};
#pragma unroll
      for (int kb=0; kb<8; ++kb) {
        const bf16x8 bo = lfrag(weo_pk + ((w*8+kb)*64 + l)*8);
        const bf16x8 ay = *(const bf16x8*)((char*)s_y + ((lr*512 + kb*64 + lh*16) ^ ((lr&7)<<4)));
        acc3 = __builtin_amdgcn_mfma_f32_16x16x32_bf16(ay, bo, acc3, 0,0,0);
      }
      const int e = w*16 + lr;
      const float beo_e = beo[e];
#pragma unroll
      for (int r=0; r<4; ++r) {
        const int row = lh*4 + r;
        s_ne[row][e] = (acc3[r] + beo_e) * (mi * s_mask[j0+row]);
      }
    }
    __syncthreads();

    // ---- phase 4 MERGED (verified): LN1 -> FF1 -> FF2+LN2, rows g4 and 8+g4 ----
    const int rowA = g4, rowB = 8 + g4;
    float a0A,a1A,a0B,a1B;
    {
      const float z0 = s_et[rowA][r4]    + s_ne[rowA][r4];
      const float z1 = s_et[rowA][r4+32] + s_ne[rowA][r4+32];
      const float z2 = s_et[rowB][r4]    + s_ne[rowB][r4];
      const float z3 = s_et[rowB][r4+32] + s_ne[rowB][r4+32];
      float rsA = z0+z1, rqA = z0*z0+z1*z1;
      float rsB = z2+z3, rqB = z2*z2+z3*z3;
#pragma unroll
      for (int mk=16; mk; mk>>=1){
        rsA += __shfl_xor(rsA,mk); rqA += __shfl_xor(rqA,mk);
        rsB += __shfl_xor(rsB,mk); rqB += __shfl_xor(rqB,mk);
      }
      const float mA = rsA*(1.f/64.f), iA = rsqrtf(rqA*(1.f/64.f)-mA*mA+LN_EPS);
      const float mB = rsB*(1.f/64.f), iB = rsqrtf(rqB*(1.f/64.f)-mB*mB+LN_EPS);
      const float g0 = gE1[r4], g1v = gE1[r4+32], b0 = bnE1[r4], b1v = bnE1[r4+32];
      a0A=(z0-mA)*iA*g0+b0;  a1A=(z1-mA)*iA*g1v+b1v;
      a0B=(z2-mB)*iB*g0+b0;  a1B=(z3-mB)*iB*g1v+b1v;
      s_ne[rowA][r4]=a0A; s_ne[rowA][r4+32]=a1A;
      s_ne[rowB][r4]=a0B; s_ne[rowB][r4+32]=a1B;
    }
    __syncthreads();

    {
      const float* s_e1n = &s_ne[0][0];   // [16][64]
      float* s_hid = (float*)s_y;         // [16][128] = 8KB exact
      float hA0=bE1[r4], hA1=bE1[r4+32], hA2=bE1[r4+64], hA3=bE1[r4+96];
      float hB0=hA0, hB1=hA1, hB2=hA2, hB3=hA3;
#pragma unroll 1
      for (int cc=0; cc<8; ++cc) {
        const float4 aaA = ((const float4*)&s_e1n[rowA*64 + cc*8])[0];
        const float4 abA = ((const float4*)&s_e1n[rowA*64 + cc*8])[1];
        const float4 aaB = ((const float4*)&s_e1n[rowB*64 + cc*8])[0];
        const float4 abB = ((const float4*)&s_e1n[rowB*64 + cc*8])[1];
        { const uint4 wq = ((const uint4*)s_we1)[cc*128 + r4];      UNPK(wq,f0); DOT8N(hA0,aaA,abA,f0); DOT8N(hB0,aaB,abB,f0); }
        { const uint4 wq = ((const uint4*)s_we1)[cc*128 + r4+32];   UNPK(wq,f1); DOT8N(hA1,aaA,abA,f1); DOT8N(hB1,aaB,abB,f1); }
        { const uint4 wq = ((const uint4*)s_we1)[cc*128 + r4+64];   UNPK(wq,f2); DOT8N(hA2,aaA,abA,f2); DOT8N(hB2,aaB,abB,f2); }
        { const uint4 wq = ((const uint4*)s_we1)[cc*128 + r4+96];   UNPK(wq,f3); DOT8N(hA3,aaA,abA,f3); DOT8N(hB3,aaB,abB,f3); }
      }
      s_hid[rowA*128 + r4]    = fmaxf(hA0,0.f);
      s_hid[rowA*128 + r4+32] = fmaxf(hA1,0.f);
      s_hid[rowA*128 + r4+64] = fmaxf(hA2,0.f);
      s_hid[rowA*128 + r4+96] = fmaxf(hA3,0.f);
      s_hid[rowB*128 + r4]    = fmaxf(hB0,0.f);
      s_hid[rowB*128 + r4+32] = fmaxf(hB1,0.f);
      s_hid[rowB*128 + r4+64] = fmaxf(hB2,0.f);
      s_hid[rowB*128 + r4+96] = fmaxf(hB3,0.f);
    }
    __syncthreads();

    {
      const float* s_hid = (const float*)s_y;
      float aA0=bE2[r4], aA1=bE2[r4+32];
      float aB0=aA0, aB1=aA1;
#pragma unroll 1
      for (int cc=0; cc<16; ++cc) {
        const float4 hAa = ((const float4*)&s_hid[rowA*128 + cc*8])[0];
        const float4 hAb = ((const float4*)&s_hid[rowA*128 + cc*8])[1];
        const float4 hBa = ((const float4*)&s_hid[rowB*128 + cc*8])[0];
        const float4 hBb = ((const float4*)&s_hid[rowB*128 + cc*8])[1];
        { const uint4 wg = ((const uint4*)s_we2)[cc*64 + r4];      UNPK(wg,gA); DOT8N(aA0,hAa,hAb,gA); DOT8N(aB0,hBa,hBb,gA); }
        { const uint4 wg = ((const uint4*)s_we2)[cc*64 + r4+32];   UNPK(wg,gB); DOT8N(aA1,hAa,hAb,gB); DOT8N(aB1,hBa,hBb,gB); }
      }
      const float zA0 = a0A + aA0, zA1 = a1A + aA1;
      const float zB0 = a0B + aB0, zB1 = a1B + aB1;
      float rsA = zA0+zA1, rqA = zA0*zA0+zA1*zA1;
      float rsB = zB0+zB1, rqB = zB0*zB0+zB1*zB1;
#pragma unroll
      for (int mk=16; mk; mk>>=1){
        rsA += __shfl_xor(rsA,mk); rqA += __shfl_xor(rqA,mk);
        rsB += __shfl_xor(rsB,mk); rqB += __shfl_xor(rqB,mk);
      }
      const float mA = rsA*(1.f/64.f), iA = rsqrtf(rqA*(1.f/64.f)-mA*mA+LN_EPS);
      const float mB = rsB*(1.f/64.f), iB = rsqrtf(rqB*(1.f/64.f)-mB*mB+LN_EPS);
      const float g0 = gE2[r4], g1v = gE2[r4+32], b0 = bnE2[r4], b1v = bnE2[r4+32];
      const size_t eA = ((size_t)bi*256 + (size_t)(j0+rowA))*64;
      const size_t eB = ((size_t)bi*256 + (size_t)(j0+rowB))*64;
      Eout[eA + r4]    = (zA0-mA)*iA*g0+b0;
      Eout[eA + r4+32] = (zA1-mA)*iA*g1v+b1v;
      Eout[eB + r4]    = (zB0-mB)*iB*g0+b0;
      Eout[eB + r4+32] = (zB1-mB)*iB*g1v+b1v;
    }
    // no trailing barrier (verified): LN2 is register-only; the stage barrier orders reuse.
  }

  // ---- WV: butterfly-merge distributed softmax states across the 4 lh groups ----
#define MERGE(nt) { \
    float m = sm##nt, L = sl##nt, A = sa##nt; \
    { float m2=__shfl_xor(m,16), L2=__shfl_xor(L,16), A2=__shfl_xor(A,16); \
      float mn=fmaxf(m,m2); float s1=__expf(m-mn), s2=__expf(m2-mn); \
      L = L*s1 + L2*s2; A = A*s1 + A2*s2; m = mn; } \
    { float m2=__shfl_xor(m,32), L2=__shfl_xor(L,32), A2=__shfl_xor(A,32); \
      float mn=fmaxf(m,m2); float s1=__expf(m-mn), s2=__expf(m2-mn); \
      L = L*s1 + L2*s2; A = A*s1 + A2*s2; m = mn; } \
    if (lh == 0) WV[(size_t)bi*256 + dcol##nt] = (L > 0.f) ? (A / L) : 0.f; }
  MERGE(0) MERGE(1) MERGE(2) MERGE(3)
#undef MERGE
}

// ---------- X path: 1 row per block; unroll-4 weight streams ----------
__launch_bounds__(256)
__global__ void xpath_kernel(const float* __restrict__ X, const int* __restrict__ mask,
  const float* __restrict__ WVg, const float* __restrict__ Wxo, const float* __restrict__ bxo,
  const float* __restrict__ WX1, const float* __restrict__ bX1,
  const float* __restrict__ WX2, const float* __restrict__ bX2,
  const float* __restrict__ gX1, const float* __restrict__ bnX1,
  const float* __restrict__ gX2, const float* __restrict__ bnX2,
  float* __restrict__ Xout)
{
  const int t = threadIdx.x, d = t;
  const int r = blockIdx.x;
  __shared__ float s_a[256];      // wv, then x1 staging
  __shared__ float s_hid[1024];
  __shared__ float s_red[8];

  const float x0 = X[(size_t)r*256 + d];
  s_a[d] = WVg[(size_t)r*256 + d];
  const float mf = (mask[r] != 0) ? 1.f : 0.f;
  __syncthreads();

  float nx = 0.f;
#pragma unroll 4
  for (int c=0;c<256;++c) nx += s_a[c] * Wxo[c*256 + d];
  const float z = x0 + (nx + bxo[d]) * mf;

  // LN1: block-wide 256 reduction (wave shfl + 4-partial combine)
  {
    float s=z, q=z*z;
#pragma unroll
    for (int mk=32; mk; mk>>=1){ s += __shfl_xor(s,mk); q += __shfl_xor(q,mk); }
    if ((t&63)==0){ s_red[t>>6]=s; s_red[4+(t>>6)]=q; }
  }
  __syncthreads();
  const float sum1 = s_red[0]+s_red[1]+s_red[2]+s_red[3];
  const float sq1  = s_red[4]+s_red[5]+s_red[6]+s_red[7];
  const float mean1 = sum1*(1.f/256.f);
  const float inv1  = rsqrtf(sq1*(1.f/256.f) - mean1*mean1 + LN_EPS);
  const float x1 = (z-mean1)*inv1*gX1[d] + bnX1[d];
  s_a[d] = x1;
  __syncthreads();

  // FF1: 4 hidden cols per thread
  float h0=bX1[t], h1=bX1[t+256], h2=bX1[t+512], h3=bX1[t+768];
#pragma unroll 4
  for (int c=0;c<256;++c){
    const float a = s_a[c];
    h0 += a * WX1[(size_t)c*1024 + t];
    h1 += a * WX1[(size_t)c*1024 + t + 256];
    h2 += a * WX1[(size_t)c*1024 + t + 512];
    h3 += a * WX1[(size_t)c*1024 + t + 768];
  }
  s_hid[t]     = fmaxf(h0,0.f);
  s_hid[t+256] = fmaxf(h1,0.f);
  s_hid[t+512] = fmaxf(h2,0.f);
  s_hid[t+768] = fmaxf(h3,0.f);
  __syncthreads();

  // FF2
  float f2 = 0.f;
#pragma unroll 8
  for (int hh=0; hh<1024; ++hh) f2 += s_hid[hh] * WX2[(size_t)hh*256 + d];
  const float z2 = x1 + f2 + bX2[d];

  // LN2: block-wide reduction
  {
    float s=z2, q=z2*z2;
#pragma unroll
    for (int mk=32; mk; mk>>=1){ s += __shfl_xor(s,mk); q += __shfl_xor(q,mk); }
    if ((t&63)==0){ s_red[t>>6]=s; s_red[4+(t>>6)]=q; }
  }
  __syncthreads();
  const float sum2 = s_red[0]+s_red[1]+s_red[2]+s_red[3];
  const float sq2  = s_red[4]+s_red[5]+s_red[6]+s_red[7];
  const float mean2 = sum2*(1.f/256.f);
  const float inv2  = rsqrtf(sq2*(1.f/256.f) - mean2*mean2 + LN_EPS);
  Xout[(size_t)r*256 + d] = (z2-mean2)*inv2*gX2[d] + bnX2[d];
}

extern "C" void kernel_launch(void* const* d_in, const int* in_sizes, int n_in,
                              void* d_out, int out_size, void* d_ws, size_t ws_size,
                              hipStream_t stream)
{
  const float* X   = (const float*)d_in[0];
  const float* E   = (const float*)d_in[1];
  const int*  mask = (const int*)  d_in[2];
  const float* Wq  = (const float*)d_in[3];
  const float* bq  = (const float*)d_in[4];
  const float* Wk  = (const float*)d_in[5];
  const float* bk  = (const float*)d_in[6];
  const float* Wv  = (const float*)d_in[7];
  const float* bv  = (const float*)d_in[8];
  const float* Wem = (const float*)d_in[9];
  const float* bem = (const float*)d_in[10];
  const float* Wea = (const float*)d_in[11];
  const float* bea = (const float*)d_in[12];
  const float* Wxo = (const float*)d_in[13];
  const float* bxo = (const float*)d_in[14];
  const float* Weo = (const float*)d_in[15];
  const float* beo = (const float*)d_in[16];
  const float* WX1 = (const float*)d_in[17];
  const float* bX1 = (const float*)d_in[18];
  const float* WX2 = (const float*)d_in[19];
  const float* bX2 = (const float*)d_in[20];
  const float* gX1 = (const float*)d_in[21];
  const float* bnX1= (const float*)d_in[22];
  const float* gX2 = (const float*)d_in[23];
  const float* bnX2= (const float*)d_in[24];
  const float* WE1 = (const float*)d_in[25];
  const float* bE1 = (const float*)d_in[26];
  const float* WE2 = (const float*)d_in[27];
  const float* bE2 = (const float*)d_in[28];
  const float* gE1 = (const float*)d_in[29];
  const float* bnE1= (const float*)d_in[30];
  const float* gE2 = (const float*)d_in[31];
  const float* bnE2= (const float*)d_in[32];

  float* out = (float*)d_out;          // Xout [262144] then Eout [16777216]
  float* wsf = (float*)d_ws;
  float* Q   = wsf;                    // [1024][256]
  float* K   = wsf + 262144;
  float* V   = wsf + 524288;
  float* WVp = wsf + 786432;
  u16* wcm    = (u16*)(wsf + 1048576); // 128KB packed weights
  u16* wem_pk = wcm;
  u16* wea_pk = wcm + 16384;
  u16* weo_pk = wcm + 32768;
  u16* we1_cm = wcm + 49152;
  u16* we2_cm = wcm + 57344;

  prep_weights<<<256,256,0,stream>>>(Wem,Wea,Weo,WE1,WE2, wem_pk,wea_pk,weo_pk,we1_cm,we2_cm);
  qkv_kernel<<<256,256,0,stream>>>(X, mask, Wq,bq,Wk,bk,Wv,bv, Q,K,V);
  heavy_kernel<<<1024,256,0,stream>>>(E, mask, Q,K,V, bem,bea,beo,bE1,bE2,
                                      gE1,bnE1,gE2,bnE2,
                                      wem_pk,wea_pk,weo_pk,we1_cm,we2_cm,
                                      WVp, out + 262144);
  xpath_kernel<<<1024,256,0,stream>>>(X, mask, WVp, Wxo,bxo,WX1,bX1,WX2,bX2,
                                      gX1,bnX1,gX2,bnX2, out);
}

// Round 22
// 652.482 us; speedup vs baseline: 1.0060x; 1.0060x over previous
//
#include <hip/hip_runtime.h>
#include <hip/hip_bf16.h>
#include <math.h>

typedef unsigned short u16;
typedef unsigned int   u32;
typedef __attribute__((ext_vector_type(8))) short bf16x8;
typedef __attribute__((ext_vector_type(4))) float f32x4;

#define LN_EPS 1e-5f
#define RS_QK  0.17677669529663687f   // 1/sqrt(32)

#define BFLO(u) __uint_as_float((u)<<16)
#define BFHI(u) __uint_as_float((u)&0xffff0000u)
#define UNPK(Wv_,p) const float p##0=BFLO((Wv_).x), p##1=BFHI((Wv_).x), \
                                p##2=BFLO((Wv_).y), p##3=BFHI((Wv_).y), \
                                p##4=BFLO((Wv_).z), p##5=BFHI((Wv_).z), \
                                p##6=BFLO((Wv_).w), p##7=BFHI((Wv_).w)
#define DOT8N(acc,va_,vb_,p) acc += (va_).x*p##0 + (va_).y*p##1 + (va_).z*p##2 + (va_).w*p##3 \
                                  + (vb_).x*p##4 + (vb_).y*p##5 + (vb_).z*p##6 + (vb_).w*p##7

__device__ __forceinline__ u16 f2bf(float x){   // software RNE (prep)
  u32 u = __float_as_uint(x);
  u32 r = (u + 0x7fffu + ((u>>16)&1u)) >> 16;
  return (u16)r;
}
__device__ __forceinline__ u16 f2bf_fast(float x){
  __hip_bfloat16 h = __float2bfloat16(x);
  return *(u16*)&h;
}

// weo B-frag via 4 volatile u32 loads (r11/r13/r16/r17-verified; never LICM-hoisted).
__device__ __forceinline__ bf16x8 lfrag(const u16* p){
  const volatile u32* q = (const volatile u32*)p;
  const u32 a=q[0], b=q[1], c=q[2], d=q[3];
  bf16x8 r;
  r[0]=(short)(a&0xffffu); r[1]=(short)(a>>16);
  r[2]=(short)(b&0xffffu); r[3]=(short)(b>>16);
  r[4]=(short)(c&0xffffu); r[5]=(short)(c>>16);
  r[6]=(short)(d&0xffffu); r[7]=(short)(d>>16);
  return r;
}

// ---------- prep: Wem/Wea/Weo in MFMA B-frag order; WE1/WE2 chunk-major (scalar FFN) ----------
__global__ void prep_weights(const float* __restrict__ Wem, const float* __restrict__ Wea,
                             const float* __restrict__ Weo, const float* __restrict__ WE1,
                             const float* __restrict__ WE2,
                             u16* __restrict__ wem_pk, u16* __restrict__ wea_pk,
                             u16* __restrict__ weo_pk, u16* __restrict__ we1_cm,
                             u16* __restrict__ we2_cm)
{
  int g = blockIdx.x*256 + threadIdx.x;
  if (g < 16384) {                    // Wem (64x256): nt<16, kb<2
    int i=g&7, lane=(g>>3)&63, kb=(g>>9)&1, nt=g>>10;
    wem_pk[g] = f2bf(Wem[(kb*32+(lane>>4)*8+i)*256 + nt*16 + (lane&15)]);
  } else if (g < 32768) {             // Wea
    int x=g-16384; int i=x&7, lane=(x>>3)&63, kb=(x>>9)&1, nt=x>>10;
    wea_pk[x] = f2bf(Wea[(kb*32+(lane>>4)*8+i)*256 + nt*16 + (lane&15)]);
  } else if (g < 49152) {             // Weo (256x64): nt<4, kb<8
    int x=g-32768; int i=x&7, lane=(x>>3)&63, kb=(x>>9)&7, nt=x>>12;
    weo_pk[x] = f2bf(Weo[(kb*32+(lane>>4)*8+i)*64 + nt*16 + (lane&15)]);
  } else if (g < 57344) {             // WE1 (64x128): [cc<8][h<128][k<8]
    int x=g-49152; int cc=x>>10, h=(x>>3)&127, k=x&7;
    we1_cm[x] = f2bf(WE1[(cc*8+k)*128 + h]);
  } else {                            // WE2 (128x64): [cc<16][e<64][k<8]
    int x=g-57344; int cc=x>>9, e=(x>>3)&63, k=x&7;
    we2_cm[x] = f2bf(WE2[(cc*8+k)*64 + e]);
  }
}

// ---------- QKV: Q/K/V = (X@W + b) * mask, 4 rows per block; unroll-4 weight stream ----------
__launch_bounds__(256)
__global__ void qkv_kernel(const float* __restrict__ X, const int* __restrict__ mask,
  const float* __restrict__ Wq, const float* __restrict__ bq,
  const float* __restrict__ Wk, const float* __restrict__ bk,
  const float* __restrict__ Wv, const float* __restrict__ bv,
  float* __restrict__ Q, float* __restrict__ K, float* __restrict__ V)
{
  const int t = threadIdx.x, d = t;
  const int r0 = blockIdx.x * 4;
  __shared__ float s_x[4][256];
  __shared__ float s_m[4];
#pragma unroll
  for (int rr=0;rr<4;++rr) s_x[rr][d] = X[(size_t)(r0+rr)*256 + d];
  if (t<4) s_m[t] = (mask[r0+t]!=0)?1.f:0.f;
  __syncthreads();
  float qa0=0,qa1=0,qa2=0,qa3=0;
  float ka0=0,ka1=0,ka2=0,ka3=0;
  float va0=0,va1=0,va2=0,va3=0;
#pragma unroll 4
  for (int c=0;c<256;++c){
    const float wq = Wq[c*256+d], wk = Wk[c*256+d], wv = Wv[c*256+d];
#define QKV1(rr) { const float xv = s_x[rr][c]; qa##rr+=xv*wq; ka##rr+=xv*wk; va##rr+=xv*wv; }
    QKV1(0) QKV1(1) QKV1(2) QKV1(3)
#undef QKV1
  }
  const float bqd=bq[d], bkd=bk[d], bvd=bv[d];
#define QKVW(rr) { const float mf = s_m[rr]; const size_t o = (size_t)(r0+rr)*256 + d; \
    Q[o]=(qa##rr+bqd)*mf; K[o]=(ka##rr+bkd)*mf; V[o]=(va##rr+bvd)*mf; }
  QKVW(0) QKVW(1) QKVW(2) QKVW(3)
#undef QKVW
}

// ---------- heavy: MFMA phases 1-3 (+lfrag weo), scalar phase 4 MERGED (r16/r17-verified) ----------
__launch_bounds__(256, 2)
__global__ void heavy_kernel(const float* __restrict__ E, const int* __restrict__ mask,
  const float* __restrict__ Qg, const float* __restrict__ Kg, const float* __restrict__ Vg,
  const float* __restrict__ bem, const float* __restrict__ bea, const float* __restrict__ beo,
  const float* __restrict__ bE1, const float* __restrict__ bE2,
  const float* __restrict__ gE1, const float* __restrict__ bnE1,
  const float* __restrict__ gE2, const float* __restrict__ bnE2,
  const u16* __restrict__ wem_pk, const u16* __restrict__ wea_pk, const u16* __restrict__ weo_pk,
  const u16* __restrict__ we1_cm, const u16* __restrict__ we2_cm,
  float* __restrict__ WV, float* __restrict__ Eout)
{
  const int t  = threadIdx.x;
  const int w  = t>>6, l = t&63;
  const int lr = l&15, lh = l>>4;
  const int bi = blockIdx.x;
  const int rb = (bi >> 8) << 8;

  __shared__ u16   s_we1[8192];          // 16KB FFN W1 chunk-major (scalar path)
  __shared__ u16   s_we2[8192];          // 16KB FFN W2 chunk-major
  __shared__ float s_et[16][64];         // 4KB  f32 E tile
  __shared__ __align__(16) u16 s_eb[1024]; // 2KB bf16 E tile (swz)
  __shared__ __align__(16) u16 s_y[4096];  // 8KB bf16 Y (swz); phase-4 overlay: hid [16][128] f32
  __shared__ float s_ne[16][64];         // 4KB newE; phase-4 overlay: e1n (in-place)
  __shared__ float s_mask[256];          // 1KB

  {
    const uint4* s1 = (const uint4*)we1_cm; uint4* d1 = (uint4*)s_we1;
    const uint4* s2 = (const uint4*)we2_cm; uint4* d2 = (uint4*)s_we2;
    for (int k=t; k<1024; k+=256){ d1[k]=s1[k]; d2[k]=s2[k]; }
    s_mask[t] = (mask[rb + t] != 0) ? 1.f : 0.f;
  }
  const float mi = (mask[bi] != 0) ? 1.f : 0.f;

  // hoisted chunk-invariant Wem/Wea B fragments (64 VGPRs)
  bf16x8 bm0,bm1,bm2,bm3,bm4,bm5,bm6,bm7;
  bf16x8 ba0,ba1,ba2,ba3,ba4,ba5,ba6,ba7;
  {
    const bf16x8* pm = (const bf16x8*)wem_pk;
    const bf16x8* pa = (const bf16x8*)wea_pk;
#define LB(nt,kb,vm,va_) vm = pm[((4*w+nt)*2+kb)*64 + l]; va_ = pa[((4*w+nt)*2+kb)*64 + l];
    LB(0,0,bm0,ba0) LB(0,1,bm1,ba1) LB(1,0,bm2,ba2) LB(1,1,bm3,ba3)
    LB(2,0,bm4,ba4) LB(2,1,bm5,ba5) LB(3,0,bm6,ba6) LB(3,1,bm7,ba7)
#undef LB
  }

  const int dcol0=(4*w+0)*16+lr, dcol1=(4*w+1)*16+lr, dcol2=(4*w+2)*16+lr, dcol3=(4*w+3)*16+lr;
  const float qv0=Qg[(size_t)bi*256+dcol0], qv1=Qg[(size_t)bi*256+dcol1],
              qv2=Qg[(size_t)bi*256+dcol2], qv3=Qg[(size_t)bi*256+dcol3];
  const float bm_0=bem[dcol0], bm_1=bem[dcol1], bm_2=bem[dcol2], bm_3=bem[dcol3];
  const float ba_0=bea[dcol0], ba_1=bea[dcol1], ba_2=bea[dcol2], ba_3=bea[dcol3];

  float sm0=-3.0e38f, sm1=-3.0e38f, sm2=-3.0e38f, sm3=-3.0e38f;
  float sl0=0.f, sl1=0.f, sl2=0.f, sl3=0.f;
  float sa0=0.f, sa1=0.f, sa2=0.f, sa3=0.f;

  const int g4 = t>>5, r4 = t&31;      // phase-4 layout (row groups, 32-lane cols)

  __syncthreads();

#pragma unroll 1
  for (int ch=0; ch<16; ++ch) {
    const int j0 = ch*16;
    {
      const float4 ev = ((const float4*)(E + ((size_t)bi*256 + j0)*64))[t];
      const int row = t>>4, c4 = (t&15)*4;
      *(float4*)&s_et[row][c4] = ev;
      ushort4 h; h.x=f2bf_fast(ev.x); h.y=f2bf_fast(ev.y); h.z=f2bf_fast(ev.z); h.w=f2bf_fast(ev.w);
      const int byt = (row*128 + c4*2) ^ ((row&7)<<4);
      *(ushort4*)((char*)s_eb + byt) = h;
    }
    __syncthreads();

    // ---- phases 1+2 fused per nt (verified) ----
    const bf16x8 af0 = *(const bf16x8*)((char*)s_eb + ((lr*128 +  0 + lh*16) ^ ((lr&7)<<4)));
    const bf16x8 af1 = *(const bf16x8*)((char*)s_eb + ((lr*128 + 64 + lh*16) ^ ((lr&7)<<4)));
#define NTBLK(HM0,HM1,HA0,HA1, qvv,bmv,bav,dcv, smv,slv,sav) { \
    f32x4 e1f={0,0,0,0}, e2f={0,0,0,0}; \
    e1f = __builtin_amdgcn_mfma_f32_16x16x32_bf16(af0, HM0, e1f,0,0,0); \
    e1f = __builtin_amdgcn_mfma_f32_16x16x32_bf16(af1, HM1, e1f,0,0,0); \
    e2f = __builtin_amdgcn_mfma_f32_16x16x32_bf16(af0, HA0, e2f,0,0,0); \
    e2f = __builtin_amdgcn_mfma_f32_16x16x32_bf16(af1, HA1, e2f,0,0,0); \
    _Pragma("unroll") \
    for (int r=0;r<4;++r){ \
      const int jrow = lh*4+r; const int jr = j0+jrow; \
      const float mj = s_mask[jr]; const float pm = mi*mj; \
      const float e1 = (e1f[r]+bmv)*pm, e2 = (e2f[r]+bav)*pm; \
      float y = qvv * Kg[(size_t)(rb+jr)*256 + dcv] * RS_QK; \
      y = y*(e1+1.f)+e2; \
      *(u16*)((char*)s_y + ((jrow*512 + dcv*2) ^ ((jrow&7)<<4))) = f2bf_fast(y); \
      if (mj>0.f){ const float mn=fmaxf(smv,y); const float sc=__expf(smv-mn); \
        const float p=__expf(y-mn); \
        slv = slv*sc+p; sav = sav*sc + p*Vg[(size_t)(rb+jr)*256 + dcv]; smv=mn; } } }
    NTBLK(bm0,bm1,ba0,ba1, qv0,bm_0,ba_0,dcol0, sm0,sl0,sa0)
    NTBLK(bm2,bm3,ba2,ba3, qv1,bm_1,ba_1,dcol1, sm1,sl1,sa1)
    NTBLK(bm4,bm5,ba4,ba5, qv2,bm_2,ba_2,dcol2, sm2,sl2,sa2)
    NTBLK(bm6,bm7,ba6,ba7, qv3,bm_3,ba_3,dcol3, sm3,sl3,sa3)
#undef NTBLK
    __syncthreads();

    // ---- phase 3 (MFMA): newE = Y @ Weo; e-tile = w; B-frags via lfrag (verified) ----
    {
      f32x4 acc3 = {0,0,0,0};
#pragma unroll
      for (int kb=0; kb<8; ++kb) {
        const bf16x8 bo = lfrag(weo_pk + ((w*8+kb)*64 + l)*8);
        const bf16x8 ay = *(const bf16x8*)((char*)s_y + ((lr*512 + kb*64 + lh*16) ^ ((lr&7)<<4)));
        acc3 = __builtin_amdgcn_mfma_f32_16x16x32_bf16(ay, bo, acc3, 0,0,0);
      }
      const int e = w*16 + lr;
      const float beo_e = beo[e];
#pragma unroll
      for (int r=0; r<4; ++r) {
        const int row = lh*4 + r;
        s_ne[row][e] = (acc3[r] + beo_e) * (mi * s_mask[j0+row]);
      }
    }
    __syncthreads();

    // ---- phase 4 MERGED (verified): LN1 -> FF1 -> FF2+LN2, rows g4 and 8+g4 ----
    const int rowA = g4, rowB = 8 + g4;
    float a0A,a1A,a0B,a1B;
    {
      const float z0 = s_et[rowA][r4]    + s_ne[rowA][r4];
      const float z1 = s_et[rowA][r4+32] + s_ne[rowA][r4+32];
      const float z2 = s_et[rowB][r4]    + s_ne[rowB][r4];
      const float z3 = s_et[rowB][r4+32] + s_ne[rowB][r4+32];
      float rsA = z0+z1, rqA = z0*z0+z1*z1;
      float rsB = z2+z3, rqB = z2*z2+z3*z3;
#pragma unroll
      for (int mk=16; mk; mk>>=1){
        rsA += __shfl_xor(rsA,mk); rqA += __shfl_xor(rqA,mk);
        rsB += __shfl_xor(rsB,mk); rqB += __shfl_xor(rqB,mk);
      }
      const float mA = rsA*(1.f/64.f), iA = rsqrtf(rqA*(1.f/64.f)-mA*mA+LN_EPS);
      const float mB = rsB*(1.f/64.f), iB = rsqrtf(rqB*(1.f/64.f)-mB*mB+LN_EPS);
      const float g0 = gE1[r4], g1v = gE1[r4+32], b0 = bnE1[r4], b1v = bnE1[r4+32];
      a0A=(z0-mA)*iA*g0+b0;  a1A=(z1-mA)*iA*g1v+b1v;
      a0B=(z2-mB)*iB*g0+b0;  a1B=(z3-mB)*iB*g1v+b1v;
      s_ne[rowA][r4]=a0A; s_ne[rowA][r4+32]=a1A;
      s_ne[rowB][r4]=a0B; s_ne[rowB][r4+32]=a1B;
    }
    __syncthreads();

    {
      const float* s_e1n = &s_ne[0][0];   // [16][64]
      float* s_hid = (float*)s_y;         // [16][128] = 8KB exact
      float hA0=bE1[r4], hA1=bE1[r4+32], hA2=bE1[r4+64], hA3=bE1[r4+96];
      float hB0=hA0, hB1=hA1, hB2=hA2, hB3=hA3;
#pragma unroll 1
      for (int cc=0; cc<8; ++cc) {
        const float4 aaA = ((const float4*)&s_e1n[rowA*64 + cc*8])[0];
        const float4 abA = ((const float4*)&s_e1n[rowA*64 + cc*8])[1];
        const float4 aaB = ((const float4*)&s_e1n[rowB*64 + cc*8])[0];
        const float4 abB = ((const float4*)&s_e1n[rowB*64 + cc*8])[1];
        { const uint4 wq = ((const uint4*)s_we1)[cc*128 + r4];      UNPK(wq,f0); DOT8N(hA0,aaA,abA,f0); DOT8N(hB0,aaB,abB,f0); }
        { const uint4 wq = ((const uint4*)s_we1)[cc*128 + r4+32];   UNPK(wq,f1); DOT8N(hA1,aaA,abA,f1); DOT8N(hB1,aaB,abB,f1); }
        { const uint4 wq = ((const uint4*)s_we1)[cc*128 + r4+64];   UNPK(wq,f2); DOT8N(hA2,aaA,abA,f2); DOT8N(hB2,aaB,abB,f2); }
        { const uint4 wq = ((const uint4*)s_we1)[cc*128 + r4+96];   UNPK(wq,f3); DOT8N(hA3,aaA,abA,f3); DOT8N(hB3,aaB,abB,f3); }
      }
      s_hid[rowA*128 + r4]    = fmaxf(hA0,0.f);
      s_hid[rowA*128 + r4+32] = fmaxf(hA1,0.f);
      s_hid[rowA*128 + r4+64] = fmaxf(hA2,0.f);
      s_hid[rowA*128 + r4+96] = fmaxf(hA3,0.f);
      s_hid[rowB*128 + r4]    = fmaxf(hB0,0.f);
      s_hid[rowB*128 + r4+32] = fmaxf(hB1,0.f);
      s_hid[rowB*128 + r4+64] = fmaxf(hB2,0.f);
      s_hid[rowB*128 + r4+96] = fmaxf(hB3,0.f);
    }
    __syncthreads();

    {
      const float* s_hid = (const float*)s_y;
      float aA0=bE2[r4], aA1=bE2[r4+32];
      float aB0=aA0, aB1=aA1;
#pragma unroll 1
      for (int cc=0; cc<16; ++cc) {
        const float4 hAa = ((const float4*)&s_hid[rowA*128 + cc*8])[0];
        const float4 hAb = ((const float4*)&s_hid[rowA*128 + cc*8])[1];
        const float4 hBa = ((const float4*)&s_hid[rowB*128 + cc*8])[0];
        const float4 hBb = ((const float4*)&s_hid[rowB*128 + cc*8])[1];
        { const uint4 wg = ((const uint4*)s_we2)[cc*64 + r4];      UNPK(wg,gA); DOT8N(aA0,hAa,hAb,gA); DOT8N(aB0,hBa,hBb,gA); }
        { const uint4 wg = ((const uint4*)s_we2)[cc*64 + r4+32];   UNPK(wg,gB); DOT8N(aA1,hAa,hAb,gB); DOT8N(aB1,hBa,hBb,gB); }
      }
      const float zA0 = a0A + aA0, zA1 = a1A + aA1;
      const float zB0 = a0B + aB0, zB1 = a1B + aB1;
      float rsA = zA0+zA1, rqA = zA0*zA0+zA1*zA1;
      float rsB = zB0+zB1, rqB = zB0*zB0+zB1*zB1;
#pragma unroll
      for (int mk=16; mk; mk>>=1){
        rsA += __shfl_xor(rsA,mk); rqA += __shfl_xor(rqA,mk);
        rsB += __shfl_xor(rsB,mk); rqB += __shfl_xor(rqB,mk);
      }
      const float mA = rsA*(1.f/64.f), iA = rsqrtf(rqA*(1.f/64.f)-mA*mA+LN_EPS);
      const float mB = rsB*(1.f/64.f), iB = rsqrtf(rqB*(1.f/64.f)-mB*mB+LN_EPS);
      const float g0 = gE2[r4], g1v = gE2[r4+32], b0 = bnE2[r4], b1v = bnE2[r4+32];
      const size_t eA = ((size_t)bi*256 + (size_t)(j0+rowA))*64;
      const size_t eB = ((size_t)bi*256 + (size_t)(j0+rowB))*64;
      Eout[eA + r4]    = (zA0-mA)*iA*g0+b0;
      Eout[eA + r4+32] = (zA1-mA)*iA*g1v+b1v;
      Eout[eB + r4]    = (zB0-mB)*iB*g0+b0;
      Eout[eB + r4+32] = (zB1-mB)*iB*g1v+b1v;
    }
    // no trailing barrier (verified): LN2 is register-only; the stage barrier orders reuse.
  }

  // ---- WV: butterfly-merge distributed softmax states across the 4 lh groups ----
#define MERGE(nt) { \
    float m = sm##nt, L = sl##nt, A = sa##nt; \
    { float m2=__shfl_xor(m,16), L2=__shfl_xor(L,16), A2=__shfl_xor(A,16); \
      float mn=fmaxf(m,m2); float s1=__expf(m-mn), s2=__expf(m2-mn); \
      L = L*s1 + L2*s2; A = A*s1 + A2*s2; m = mn; } \
    { float m2=__shfl_xor(m,32), L2=__shfl_xor(L,32), A2=__shfl_xor(A,32); \
      float mn=fmaxf(m,m2); float s1=__expf(m-mn), s2=__expf(m2-mn); \
      L = L*s1 + L2*s2; A = A*s1 + A2*s2; m = mn; } \
    if (lh == 0) WV[(size_t)bi*256 + dcol##nt] = (L > 0.f) ? (A / L) : 0.f; }
  MERGE(0) MERGE(1) MERGE(2) MERGE(3)
#undef MERGE
}

// ---------- X path: 1 row per block; unroll-4 weight streams ----------
__launch_bounds__(256)
__global__ void xpath_kernel(const float* __restrict__ X, const int* __restrict__ mask,
  const float* __restrict__ WVg, const float* __restrict__ Wxo, const float* __restrict__ bxo,
  const float* __restrict__ WX1, const float* __restrict__ bX1,
  const float* __restrict__ WX2, const float* __restrict__ bX2,
  const float* __restrict__ gX1, const float* __restrict__ bnX1,
  const float* __restrict__ gX2, const float* __restrict__ bnX2,
  float* __restrict__ Xout)
{
  const int t = threadIdx.x, d = t;
  const int r = blockIdx.x;
  __shared__ float s_a[256];      // wv, then x1 staging
  __shared__ float s_hid[1024];
  __shared__ float s_red[8];

  const float x0 = X[(size_t)r*256 + d];
  s_a[d] = WVg[(size_t)r*256 + d];
  const float mf = (mask[r] != 0) ? 1.f : 0.f;
  __syncthreads();

  float nx = 0.f;
#pragma unroll 4
  for (int c=0;c<256;++c) nx += s_a[c] * Wxo[c*256 + d];
  const float z = x0 + (nx + bxo[d]) * mf;

  // LN1: block-wide 256 reduction (wave shfl + 4-partial combine)
  {
    float s=z, q=z*z;
#pragma unroll
    for (int mk=32; mk; mk>>=1){ s += __shfl_xor(s,mk); q += __shfl_xor(q,mk); }
    if ((t&63)==0){ s_red[t>>6]=s; s_red[4+(t>>6)]=q; }
  }
  __syncthreads();
  const float sum1 = s_red[0]+s_red[1]+s_red[2]+s_red[3];
  const float sq1  = s_red[4]+s_red[5]+s_red[6]+s_red[7];
  const float mean1 = sum1*(1.f/256.f);
  const float inv1  = rsqrtf(sq1*(1.f/256.f) - mean1*mean1 + LN_EPS);
  const float x1 = (z-mean1)*inv1*gX1[d] + bnX1[d];
  s_a[d] = x1;
  __syncthreads();

  // FF1: 4 hidden cols per thread
  float h0=bX1[t], h1=bX1[t+256], h2=bX1[t+512], h3=bX1[t+768];
#pragma unroll 4
  for (int c=0;c<256;++c){
    const float a = s_a[c];
    h0 += a * WX1[(size_t)c*1024 + t];
    h1 += a * WX1[(size_t)c*1024 + t + 256];
    h2 += a * WX1[(size_t)c*1024 + t + 512];
    h3 += a * WX1[(size_t)c*1024 + t + 768];
  }
  s_hid[t]     = fmaxf(h0,0.f);
  s_hid[t+256] = fmaxf(h1,0.f);
  s_hid[t+512] = fmaxf(h2,0.f);
  s_hid[t+768] = fmaxf(h3,0.f);
  __syncthreads();

  // FF2
  float f2 = 0.f;
#pragma unroll 8
  for (int hh=0; hh<1024; ++hh) f2 += s_hid[hh] * WX2[(size_t)hh*256 + d];
  const float z2 = x1 + f2 + bX2[d];

  // LN2: block-wide reduction
  {
    float s=z2, q=z2*z2;
#pragma unroll
    for (int mk=32; mk; mk>>=1){ s += __shfl_xor(s,mk); q += __shfl_xor(q,mk); }
    if ((t&63)==0){ s_red[t>>6]=s; s_red[4+(t>>6)]=q; }
  }
  __syncthreads();
  const float sum2 = s_red[0]+s_red[1]+s_red[2]+s_red[3];
  const float sq2  = s_red[4]+s_red[5]+s_red[6]+s_red[7];
  const float mean2 = sum2*(1.f/256.f);
  const float inv2  = rsqrtf(sq2*(1.f/256.f) - mean2*mean2 + LN_EPS);
  Xout[(size_t)r*256 + d] = (z2-mean2)*inv2*gX2[d] + bnX2[d];
}

extern "C" void kernel_launch(void* const* d_in, const int* in_sizes, int n_in,
                              void* d_out, int out_size, void* d_ws, size_t ws_size,
                              hipStream_t stream)
{
  const float* X   = (const float*)d_in[0];
  const float* E   = (const float*)d_in[1];
  const int*  mask = (const int*)  d_in[2];
  const float* Wq  = (const float*)d_in[3];
  const float* bq  = (const float*)d_in[4];
  const float* Wk  = (const float*)d_in[5];
  const float* bk  = (const float*)d_in[6];
  const float* Wv  = (const float*)d_in[7];
  const float* bv  = (const float*)d_in[8];
  const float* Wem = (const float*)d_in[9];
  const float* bem = (const float*)d_in[10];
  const float* Wea = (const float*)d_in[11];
  const float* bea = (const float*)d_in[12];
  const float* Wxo = (const float*)d_in[13];
  const float* bxo = (const float*)d_in[14];
  const float* Weo = (const float*)d_in[15];
  const float* beo = (const float*)d_in[16];
  const float* WX1 = (const float*)d_in[17];
  const float* bX1 = (const float*)d_in[18];
  const float* WX2 = (const float*)d_in[19];
  const float* bX2 = (const float*)d_in[20];
  const float* gX1 = (const float*)d_in[21];
  const float* bnX1= (const float*)d_in[22];
  const float* gX2 = (const float*)d_in[23];
  const float* bnX2= (const float*)d_in[24];
  const float* WE1 = (const float*)d_in[25];
  const float* bE1 = (const float*)d_in[26];
  const float* WE2 = (const float*)d_in[27];
  const float* bE2 = (const float*)d_in[28];
  const float* gE1 = (const float*)d_in[29];
  const float* bnE1= (const float*)d_in[30];
  const float* gE2 = (const float*)d_in[31];
  const float* bnE2= (const float*)d_in[32];

  float* out = (float*)d_out;          // Xout [262144] then Eout [16777216]
  float* wsf = (float*)d_ws;
  float* Q   = wsf;                    // [1024][256]
  float* K   = wsf + 262144;
  float* V   = wsf + 524288;
  float* WVp = wsf + 786432;
  u16* wcm    = (u16*)(wsf + 1048576); // 128KB packed weights
  u16* wem_pk = wcm;
  u16* wea_pk = wcm + 16384;
  u16* weo_pk = wcm + 32768;
  u16* we1_cm = wcm + 49152;
  u16* we2_cm = wcm + 57344;

  prep_weights<<<256,256,0,stream>>>(Wem,Wea,Weo,WE1,WE2, wem_pk,wea_pk,weo_pk,we1_cm,we2_cm);
  qkv_kernel<<<256,256,0,stream>>>(X, mask, Wq,bq,Wk,bk,Wv,bv, Q,K,V);
  heavy_kernel<<<1024,256,0,stream>>>(E, mask, Q,K,V, bem,bea,beo,bE1,bE2,
                                      gE1,bnE1,gE2,bnE2,
                                      wem_pk,wea_pk,weo_pk,we1_cm,we2_cm,
                                      WVp, out + 262144);
  xpath_kernel<<<1024,256,0,stream>>>(X, mask, WVp, Wxo,bxo,WX1,bX1,WX2,bX2,
                                      gX1,bnX1,gX2,bnX2, out);
}